// Round 8
// baseline (160.103 us; speedup 1.0000x reference)
//
#include <hip/hip_runtime.h>
#include <hip/hip_bf16.h>
#include <math.h>

#define BATCH 1024
#define BM 32
#define BN 64
#define BK 64
#define LDK 72   // bf16 units; 144B row stride -> 16B-aligned frags, 2-way read conflicts (free)
#define NRB 32   // row-blocks = BATCH/BM
#define NBLOCKS 256

typedef __attribute__((ext_vector_type(8))) short bf16x8;
typedef __attribute__((ext_vector_type(8))) ushort ushort8;
typedef __attribute__((ext_vector_type(4))) float f32x4;

static __device__ __forceinline__ ushort f2bf(float f) {
    union { float f; unsigned u; } v; v.f = f;
    unsigned r = (v.u + 0x7fffu + ((v.u >> 16) & 1u)) >> 16;  // RNE
    return (ushort)r;
}
static __device__ __forceinline__ float bf2f(ushort u) {
    union { unsigned u; float f; } v; v.u = ((unsigned)u) << 16;
    return v.f;
}

struct GemmSh {
    ushort As[2][BM][LDK];
    ushort Bs[2][BN][LDK];
    float bred[4 * BN];
    float xsq_s[BM], wsq_s[BN];
    float cs[2][BN], cq[2][BN];
};
struct Sh {
    union { float ptile[64][65]; GemmSh g; } u;
    float scaleK[784], shiftK[784];
};

// ---- custom grid barrier: release-fence + relaxed arrive; winner flips generation (release);
// ---- losers spin on RELAXED agent loads (no per-spin L2 invalidate) + s_sleep backoff.
static __device__ __forceinline__ void gridbar(unsigned* bar) {
    __syncthreads();
    if (threadIdx.x == 0) {
        __threadfence();   // agent release: my block's writes reach the coherence point
        unsigned* cnt = bar;
        unsigned* gen = bar + 64;   // separate cache line
        unsigned g = __hip_atomic_load(gen, __ATOMIC_RELAXED, __HIP_MEMORY_SCOPE_AGENT);
        unsigned old = __hip_atomic_fetch_add(cnt, 1u, __ATOMIC_RELAXED, __HIP_MEMORY_SCOPE_AGENT);
        if (old == NBLOCKS - 1u) {
            __hip_atomic_store(cnt, 0u, __ATOMIC_RELAXED, __HIP_MEMORY_SCOPE_AGENT);
            __hip_atomic_store(gen, g + 1u, __ATOMIC_RELEASE, __HIP_MEMORY_SCOPE_AGENT);
        } else {
            while (__hip_atomic_load(gen, __ATOMIC_RELAXED, __HIP_MEMORY_SCOPE_AGENT) == g)
                __builtin_amdgcn_s_sleep(4);
        }
        __threadfence();   // agent acquire: invalidate stale cached data before consuming
    }
    __syncthreads();
}

// ============ prep phase: W[K][N] fp32 -> Wt[N][K] bf16 (LDS-tiled transpose) ============
static __device__ void prep_phase(
    const float* __restrict__ W1, const float* __restrict__ W2,
    const float* __restrict__ W3, const float* __restrict__ W4,
    ushort* __restrict__ Wt1, ushort* __restrict__ Wt2,
    ushort* __restrict__ Wt3, ushort* __restrict__ Wt4,
    Sh& sh, int bid, int tid)
{
    const float* W; ushort* Wt; int K, N, kt, nt;
    if (bid < 91)       { W = W1; Wt = Wt1; K = 784; N = 392; kt = bid % 13;       nt = bid / 13; }
    else if (bid < 98)  { W = W2; Wt = Wt2; K = 392; N = 8;   kt = bid - 91;       nt = 0; }
    else if (bid < 105) { W = W3; Wt = Wt3; K = 8;   N = 392; kt = 0;              nt = bid - 98; }
    else                { int r = bid - 105; W = W4; Wt = Wt4; K = 392; N = 784;   kt = r % 7;    nt = r / 7; }

    const int k0 = kt * 64, n0 = nt * 64;
    #pragma unroll
    for (int it = 0; it < 16; ++it) {
        int e = it * 256 + tid;
        int kk = e >> 6, nn = e & 63;
        int gk = k0 + kk, gn = n0 + nn;
        sh.u.ptile[kk][nn] = (gk < K && gn < N) ? W[(size_t)gk * N + gn] : 0.f;
    }
    __syncthreads();
    #pragma unroll
    for (int it = 0; it < 16; ++it) {
        int e = it * 256 + tid;
        int nn = e >> 6, kk = e & 63;
        int gk = k0 + kk, gn = n0 + nn;
        if (gk < K && gn < N) Wt[(size_t)gn * K + gk] = f2bf(sh.u.ptile[kk][nn]);
    }
}

// ============ fused GEMM phase (identical math to round-7 gemm_fused) ============
template <int NORM>
static __device__ void gemm_phase(
    const float* __restrict__ A, const ushort* __restrict__ Wt,
    const float2* __restrict__ stats_in, const float* __restrict__ gamma, const float* __restrict__ beta,
    float* __restrict__ Z, float2* __restrict__ stats_out,
    int K, int N, int cx, int rb, Sh& sh, int tid)
{
    GemmSh& G = sh.u.g;
    const int lane = tid & 63;
    const int wv = tid >> 6;
    const int wr = wv >> 1, wc = wv & 1;
    const int row0 = rb * BM, col0 = cx * BN;
    const int ar = tid >> 3;
    const int ak0 = (tid & 7) * 8;
    const int bn = tid & 63;
    const int bk0 = (tid >> 6) * 16;
    const int fr = lane & 15;
    const int fg = lane >> 4;

    if (NORM) {
        for (int k = tid; k < K; k += 256) {
            double s = 0.0, q = 0.0;
            #pragma unroll 4
            for (int rr = 0; rr < NRB; ++rr) {
                float2 p = stats_in[rr * K + k];
                s += (double)p.x; q += (double)p.y;
            }
            double mean = s * (1.0 / BATCH);
            double var = q * (1.0 / BATCH) - mean * mean;
            float inv = (float)(1.0 / sqrt(var + 1e-5));
            float sc = gamma[k] * inv;
            sh.scaleK[k] = sc;
            sh.shiftK[k] = beta[k] - (float)mean * sc;
        }
        __syncthreads();
    }

    f32x4 acc[2] = {};
    float asq = 0.f;
    float bsq = 0.f;
    float areg[8];
    ushort8 bh[2];
    const int ntiles = (K + BK - 1) / BK;

    auto load_tile = [&](int t) {
        const int kbase = t * BK;
        const int gc = col0 + bn;
        if (kbase + BK <= K) {
            const float* p = A + (size_t)(row0 + ar) * K + kbase + ak0;
            f32x4 v0 = *(const f32x4*)p;
            f32x4 v1 = *(const f32x4*)(p + 4);
            #pragma unroll
            for (int j = 0; j < 4; ++j) { areg[j] = v0[j]; areg[4 + j] = v1[j]; }
            if (NORM) {
                #pragma unroll
                for (int j = 0; j < 8; ++j)
                    areg[j] = fmaxf(areg[j] * sh.scaleK[kbase + ak0 + j] + sh.shiftK[kbase + ak0 + j], 0.f);
            }
            if (gc < N) {
                const ushort* q = Wt + (size_t)gc * K + kbase + bk0;
                bh[0] = *(const ushort8*)q;
                bh[1] = *(const ushort8*)(q + 8);
            } else {
                bh[0] = (ushort8)0; bh[1] = (ushort8)0;
            }
        } else {
            #pragma unroll
            for (int j = 0; j < 8; ++j) {
                int gk = kbase + ak0 + j;
                float x = 0.f;
                if (gk < K) {
                    x = A[(size_t)(row0 + ar) * K + gk];
                    if (NORM) x = fmaxf(x * sh.scaleK[gk] + sh.shiftK[gk], 0.f);
                }
                areg[j] = x;
            }
            #pragma unroll
            for (int i = 0; i < 16; ++i) {
                int gk = kbase + bk0 + i;
                ushort u = (gk < K && gc < N) ? Wt[(size_t)gc * K + gk] : (ushort)0;
                bh[i >> 3][i & 7] = u;
            }
        }
    };

    auto store_tile = [&](int buf) {
        ushort8 h;
        #pragma unroll
        for (int j = 0; j < 8; ++j) {
            h[j] = f2bf(areg[j]);
            asq += areg[j] * areg[j];
        }
        *(ushort8*)&G.As[buf][ar][ak0] = h;
        #pragma unroll
        for (int i = 0; i < 8; ++i) {
            float f0 = bf2f(bh[0][i]); bsq += f0 * f0;
            float f1 = bf2f(bh[1][i]); bsq += f1 * f1;
        }
        *(ushort8*)&G.Bs[buf][bn][bk0] = bh[0];
        *(ushort8*)&G.Bs[buf][bn][bk0 + 8] = bh[1];
    };

    auto compute = [&](int buf) {
        bf16x8 af[2], bfr[2][2];
        #pragma unroll
        for (int kk = 0; kk < 2; ++kk)
            af[kk] = *(const bf16x8*)&G.As[buf][wr * 16 + fr][kk * 32 + fg * 8];
        #pragma unroll
        for (int n = 0; n < 2; ++n)
            #pragma unroll
            for (int kk = 0; kk < 2; ++kk)
                bfr[n][kk] = *(const bf16x8*)&G.Bs[buf][wc * 32 + n * 16 + fr][kk * 32 + fg * 8];
        #pragma unroll
        for (int n = 0; n < 2; ++n)
            #pragma unroll
            for (int kk = 0; kk < 2; ++kk)
                acc[n] = __builtin_amdgcn_mfma_f32_16x16x32_bf16(af[kk], bfr[n][kk], acc[n], 0, 0, 0);
    };

    load_tile(0);
    store_tile(0);
    __syncthreads();
    for (int t = 0; t < ntiles; ++t) {
        if (t + 1 < ntiles) load_tile(t + 1);
        compute(t & 1);
        if (t + 1 < ntiles) store_tile((t + 1) & 1);
        __syncthreads();
    }

    {
        float s = asq;
        s += __shfl_xor(s, 1, 64);
        s += __shfl_xor(s, 2, 64);
        s += __shfl_xor(s, 4, 64);
        if ((tid & 7) == 0) G.xsq_s[ar] = s;
    }
    G.bred[(tid >> 6) * BN + bn] = bsq;
    __syncthreads();
    if (tid < BN) G.wsq_s[tid] = G.bred[0*BN+tid] + G.bred[1*BN+tid] + G.bred[2*BN+tid] + G.bred[3*BN+tid];
    __syncthreads();

    #pragma unroll
    for (int n = 0; n < 2; ++n) {
        const int c64 = wc * 32 + n * 16 + fr;
        const int c = col0 + c64;
        const float wsq = G.wsq_s[c64];
        float ps = 0.f, pq = 0.f;
        #pragma unroll
        for (int j = 0; j < 4; ++j) {
            const int rl = wr * 16 + fg * 4 + j;
            float zv = acc[n][j] - 0.5f * (G.xsq_s[rl] + wsq);
            ps += zv; pq += zv * zv;
            if (c < N) Z[(size_t)(row0 + rl) * N + c] = zv;
        }
        ps += __shfl_xor(ps, 16, 64); ps += __shfl_xor(ps, 32, 64);
        pq += __shfl_xor(pq, 16, 64); pq += __shfl_xor(pq, 32, 64);
        if (fg == 0) { G.cs[wr][c64] = ps; G.cq[wr][c64] = pq; }
    }
    __syncthreads();
    if (tid < BN) {
        int c = col0 + tid;
        if (c < N)
            stats_out[rb * N + c] = make_float2(G.cs[0][tid] + G.cs[1][tid],
                                               G.cq[0][tid] + G.cq[1][tid]);
    }
    __syncthreads();
}

// ============ final BN + sigmoid phase, in place ============
static __device__ void bnsig_phase(
    float* __restrict__ Zout, const float2* __restrict__ stats,
    const float* __restrict__ gamma, const float* __restrict__ beta,
    int N, Sh& sh, int bid, int tid)
{
    for (int k = tid; k < N; k += 256) {
        double s = 0.0, q = 0.0;
        #pragma unroll 4
        for (int rr = 0; rr < NRB; ++rr) {
            float2 p = stats[rr * N + k];
            s += (double)p.x; q += (double)p.y;
        }
        double mean = s * (1.0 / BATCH);
        double var = q * (1.0 / BATCH) - mean * mean;
        float inv = (float)(1.0 / sqrt(var + 1e-5));
        float scv = gamma[k] * inv;
        sh.scaleK[k] = scv;
        sh.shiftK[k] = beta[k] - (float)mean * scv;
    }
    __syncthreads();
    const int nf4 = BATCH * N / 4;
    f32x4* p = (f32x4*)Zout;
    for (int i = bid * 256 + tid; i < nf4; i += NBLOCKS * 256) {
        f32x4 v = p[i];
        int k = (i * 4) % N;
        #pragma unroll
        for (int j = 0; j < 4; ++j) {
            float y = v[j] * sh.scaleK[k + j] + sh.shiftK[k + j];
            v[j] = 1.f / (1.f + expf(-y));
        }
        p[i] = v;
    }
}

// ============ whole network, one cooperative launch, custom barriers ============
__global__ __launch_bounds__(256) void fullnet(
    const float* X,
    const float* W1, const float* g1, const float* b1,
    const float* W2, const float* g2, const float* b2,
    const float* W3, const float* g3, const float* b3,
    const float* W4, const float* g4, const float* b4,
    float* z1, float* z2, float* z3,
    float2* st1, float2* st2, float2* st3, float2* st4,
    ushort* Wt1, ushort* Wt2, ushort* Wt3, ushort* Wt4,
    float* outp, unsigned* bar)
{
    __shared__ Sh sh;
    const int tid = threadIdx.x;
    const int bid = blockIdx.x;

    // phase 0: weight transpose+convert
    if (bid < 196) prep_phase(W1, W2, W3, W4, Wt1, Wt2, Wt3, Wt4, sh, bid, tid);
    gridbar(bar);
    // L1: X @ W1 -> z1, st1
    if (bid < 224) gemm_phase<0>(X, Wt1, nullptr, nullptr, nullptr, z1, st1,
                                 784, 392, bid / 32, bid % 32, sh, tid);
    gridbar(bar);
    // L2: relu(bn(z1)) @ W2 -> z2, st2
    if (bid < 32) gemm_phase<1>(z1, Wt2, st1, g1, b1, z2, st2,
                                392, 8, 0, bid, sh, tid);
    gridbar(bar);
    // L3: relu(bn(z2)) @ W3 -> z3, st3
    if (bid < 224) gemm_phase<1>(z2, Wt3, st2, g2, b2, z3, st3,
                                 8, 392, bid / 32, bid % 32, sh, tid);
    gridbar(bar);
    // L4: relu(bn(z3)) @ W4 -> outp (pre-BN), st4   (416 tiles over 256 blocks)
    for (int t = bid; t < 13 * 32; t += NBLOCKS)
        gemm_phase<1>(z3, Wt4, st3, g3, b3, outp, st4,
                      392, 784, t / 32, t % 32, sh, tid);
    gridbar(bar);
    // final: sigmoid(bn(outp)) in place
    bnsig_phase(outp, st4, g4, b4, 784, sh, bid, tid);
}

extern "C" void kernel_launch(void* const* d_in, const int* in_sizes, int n_in,
                              void* d_out, int out_size, void* d_ws, size_t ws_size,
                              hipStream_t stream) {
    const float* X  = (const float*)d_in[0];
    const float* W1 = (const float*)d_in[1];
    const float* g1 = (const float*)d_in[2];
    const float* b1 = (const float*)d_in[3];
    const float* W2 = (const float*)d_in[4];
    const float* g2 = (const float*)d_in[5];
    const float* b2 = (const float*)d_in[6];
    const float* W3 = (const float*)d_in[7];
    const float* g3 = (const float*)d_in[8];
    const float* b3 = (const float*)d_in[9];
    const float* W4 = (const float*)d_in[10];
    const float* g4 = (const float*)d_in[11];
    const float* b4 = (const float*)d_in[12];

    float* ws = (float*)d_ws;
    float*  z1  = ws;                               // 1024*392
    float*  z2  = z1 + 1024 * 392;                  // 1024*8
    float*  z3  = z2 + 1024 * 8;                    // 1024*392
    float2* st1 = (float2*)(z3 + 1024 * 392);       // [32][392]
    float2* st2 = st1 + NRB * 392;                  // [32][8]
    float2* st3 = st2 + NRB * 8;                    // [32][392]
    float2* st4 = st3 + NRB * 392;                  // [32][784]
    ushort* Wt1 = (ushort*)(st4 + NRB * 784);       // [392][784]
    ushort* Wt2 = Wt1 + 392 * 784;                  // [8][392]
    ushort* Wt3 = Wt2 + 8 * 392;                    // [392][8]
    ushort* Wt4 = Wt3 + 392 * 8;                    // [784][392]
    // barrier state: 256B-aligned region after Wt4
    size_t bar_off = (((size_t)((Wt4 + 784 * 392) - (ushort*)ws) * 2 + 255) / 256) * 256;
    unsigned* bar = (unsigned*)((char*)d_ws + bar_off);
    float* outp = (float*)d_out;

    hipMemsetAsync(bar, 0, 512, stream);

    void* args[] = {
        (void*)&X,
        (void*)&W1, (void*)&g1, (void*)&b1,
        (void*)&W2, (void*)&g2, (void*)&b2,
        (void*)&W3, (void*)&g3, (void*)&b3,
        (void*)&W4, (void*)&g4, (void*)&b4,
        (void*)&z1, (void*)&z2, (void*)&z3,
        (void*)&st1, (void*)&st2, (void*)&st3, (void*)&st4,
        (void*)&Wt1, (void*)&Wt2, (void*)&Wt3, (void*)&Wt4,
        (void*)&outp, (void*)&bar,
    };
    hipLaunchCooperativeKernel((void*)fullnet, dim3(NBLOCKS), dim3(256), args, 0, stream);
}

// Round 9
// 76.043 us; speedup vs baseline: 2.1054x; 2.1054x over previous
//
#include <hip/hip_runtime.h>
#include <hip/hip_bf16.h>
#include <math.h>

#define BATCH 1024
#define BM 32
#define BN 64
#define BK 64
#define LDK 72   // bf16 units; 144B row stride -> 16B-aligned frags, 2-way read conflicts (free)
#define NRB 32   // row-blocks = BATCH/BM

typedef __attribute__((ext_vector_type(8))) short bf16x8;
typedef __attribute__((ext_vector_type(8))) ushort ushort8;
typedef __attribute__((ext_vector_type(4))) float f32x4;

static __device__ __forceinline__ ushort f2bf(float f) {
    union { float f; unsigned u; } v; v.f = f;
    unsigned r = (v.u + 0x7fffu + ((v.u >> 16) & 1u)) >> 16;  // RNE
    return (ushort)r;
}
static __device__ __forceinline__ float bf2f(ushort u) {
    union { unsigned u; float f; } v; v.u = ((unsigned)u) << 16;
    return v.f;
}

struct GemmSh {
    ushort As[2][BM][LDK];
    ushort Bs[2][BN][LDK];
    float bred[4 * BN];
    float xsq_s[BM], wsq_s[BN];
    float cs[2][BN], cq[2][BN];
};
struct Sh {
    union { float ptile[64][65]; GemmSh g; } u;
    float scaleK[784], shiftK[784];
};

// ---------- stats finalize: st layout is [K][NRB] float2 (contiguous per column) ----------
static __device__ __forceinline__ void finalize_stats(
    const float2* __restrict__ stats_in, const float* __restrict__ gamma,
    const float* __restrict__ beta, int K, Sh& sh, int tid)
{
    for (int k = tid; k < K; k += 256) {
        const f32x4* p4 = (const f32x4*)(stats_in + (size_t)k * NRB);
        double s = 0.0, q = 0.0;
        #pragma unroll
        for (int i = 0; i < NRB / 2; ++i) {      // 16 x f32x4 = 32 float2, ascending rb order
            f32x4 v = p4[i];
            s += (double)v[0]; q += (double)v[1];
            s += (double)v[2]; q += (double)v[3];
        }
        double mean = s * (1.0 / BATCH);
        double var = q * (1.0 / BATCH) - mean * mean;
        float inv = (float)(1.0 / sqrt(var + 1e-5));
        float sc = gamma[k] * inv;
        sh.scaleK[k] = sc;
        sh.shiftK[k] = beta[k] - (float)mean * sc;
    }
    __syncthreads();
}

// ============ fused GEMM body ============
// BSRC=0: B staged from fp32 W[K][N] (strided); BSRC=1: from bf16 Wt[N][K] (contiguous).
// A_eff[r][k] = NORM ? relu(A[r][k]*scale_k + shift_k) : A[r][k]
// Z[r][c] = A_eff[r]·B[:,c] - 0.5*(||A_eff[r]||^2 + ||B[:,c]||^2); dot bf16 MFMA, rest fp32.
// stats_out[c][rb] = (sum_r z, sum_r z^2) over this block's BM rows.
template <int NORM, int BSRC>
static __device__ void gemm_body(
    const float* __restrict__ A, const float* __restrict__ Bw32, const ushort* __restrict__ Wt,
    const float2* __restrict__ stats_in, const float* __restrict__ gamma, const float* __restrict__ beta,
    float* __restrict__ Z, float2* __restrict__ stats_out,
    int K, int N, int cx, int rb, Sh& sh, int tid)
{
    GemmSh& G = sh.u.g;
    const int lane = tid & 63;
    const int wv = tid >> 6;
    const int wr = wv >> 1, wc = wv & 1;
    const int row0 = rb * BM, col0 = cx * BN;
    const int ar = tid >> 3;
    const int ak0 = (tid & 7) * 8;
    const int bn = tid & 63;
    const int bk0 = (tid >> 6) * 16;
    const int fr = lane & 15;
    const int fg = lane >> 4;

    if (NORM) finalize_stats(stats_in, gamma, beta, K, sh, tid);

    f32x4 acc[2] = {};
    float asq = 0.f;
    float bsq = 0.f;
    float areg[8];
    float breg[16];
    ushort8 bh[2];
    const int ntiles = (K + BK - 1) / BK;

    auto load_tile = [&](int t) {
        const int kbase = t * BK;
        const int gc = col0 + bn;
        if (kbase + BK <= K) {
            const float* p = A + (size_t)(row0 + ar) * K + kbase + ak0;
            f32x4 v0 = *(const f32x4*)p;
            f32x4 v1 = *(const f32x4*)(p + 4);
            #pragma unroll
            for (int j = 0; j < 4; ++j) { areg[j] = v0[j]; areg[4 + j] = v1[j]; }
            if (NORM) {
                #pragma unroll
                for (int j = 0; j < 8; ++j)
                    areg[j] = fmaxf(areg[j] * sh.scaleK[kbase + ak0 + j] + sh.shiftK[kbase + ak0 + j], 0.f);
            }
            if (BSRC == 0) {
                #pragma unroll
                for (int i = 0; i < 16; ++i)
                    breg[i] = (gc < N) ? Bw32[(size_t)(kbase + bk0 + i) * N + gc] : 0.f;
            } else {
                if (gc < N) {
                    const ushort* q = Wt + (size_t)gc * K + kbase + bk0;
                    bh[0] = *(const ushort8*)q;
                    bh[1] = *(const ushort8*)(q + 8);
                } else {
                    bh[0] = (ushort8)0; bh[1] = (ushort8)0;
                }
            }
        } else {
            #pragma unroll
            for (int j = 0; j < 8; ++j) {
                int gk = kbase + ak0 + j;
                float x = 0.f;
                if (gk < K) {
                    x = A[(size_t)(row0 + ar) * K + gk];
                    if (NORM) x = fmaxf(x * sh.scaleK[gk] + sh.shiftK[gk], 0.f);
                }
                areg[j] = x;
            }
            if (BSRC == 0) {
                #pragma unroll
                for (int i = 0; i < 16; ++i) {
                    int gk = kbase + bk0 + i;
                    breg[i] = (gk < K && gc < N) ? Bw32[(size_t)gk * N + gc] : 0.f;
                }
            } else {
                #pragma unroll
                for (int i = 0; i < 16; ++i) {
                    int gk = kbase + bk0 + i;
                    ushort u = (gk < K && gc < N) ? Wt[(size_t)gc * K + gk] : (ushort)0;
                    bh[i >> 3][i & 7] = u;
                }
            }
        }
    };

    auto store_tile = [&](int buf) {
        ushort8 h;
        #pragma unroll
        for (int j = 0; j < 8; ++j) {
            h[j] = f2bf(areg[j]);
            asq += areg[j] * areg[j];
        }
        *(ushort8*)&G.As[buf][ar][ak0] = h;
        if (BSRC == 0) {
            ushort8 e0, e1;
            #pragma unroll
            for (int i = 0; i < 8; ++i) {
                e0[i] = f2bf(breg[i]);      bsq += breg[i] * breg[i];
                e1[i] = f2bf(breg[8 + i]);  bsq += breg[8 + i] * breg[8 + i];
            }
            *(ushort8*)&G.Bs[buf][bn][bk0] = e0;
            *(ushort8*)&G.Bs[buf][bn][bk0 + 8] = e1;
        } else {
            #pragma unroll
            for (int i = 0; i < 8; ++i) {
                float f0 = bf2f(bh[0][i]); bsq += f0 * f0;
                float f1 = bf2f(bh[1][i]); bsq += f1 * f1;
            }
            *(ushort8*)&G.Bs[buf][bn][bk0] = bh[0];
            *(ushort8*)&G.Bs[buf][bn][bk0 + 8] = bh[1];
        }
    };

    auto compute = [&](int buf) {
        bf16x8 af[2], bfr[2][2];
        #pragma unroll
        for (int kk = 0; kk < 2; ++kk)
            af[kk] = *(const bf16x8*)&G.As[buf][wr * 16 + fr][kk * 32 + fg * 8];
        #pragma unroll
        for (int n = 0; n < 2; ++n)
            #pragma unroll
            for (int kk = 0; kk < 2; ++kk)
                bfr[n][kk] = *(const bf16x8*)&G.Bs[buf][wc * 32 + n * 16 + fr][kk * 32 + fg * 8];
        #pragma unroll
        for (int n = 0; n < 2; ++n)
            #pragma unroll
            for (int kk = 0; kk < 2; ++kk)
                acc[n] = __builtin_amdgcn_mfma_f32_16x16x32_bf16(af[kk], bfr[n][kk], acc[n], 0, 0, 0);
    };

    load_tile(0);
    store_tile(0);
    __syncthreads();
    for (int t = 0; t < ntiles; ++t) {
        if (t + 1 < ntiles) load_tile(t + 1);
        compute(t & 1);
        if (t + 1 < ntiles) store_tile((t + 1) & 1);
        __syncthreads();
    }

    {
        float s = asq;
        s += __shfl_xor(s, 1, 64);
        s += __shfl_xor(s, 2, 64);
        s += __shfl_xor(s, 4, 64);
        if ((tid & 7) == 0) G.xsq_s[ar] = s;
    }
    G.bred[(tid >> 6) * BN + bn] = bsq;
    __syncthreads();
    if (tid < BN) G.wsq_s[tid] = G.bred[0*BN+tid] + G.bred[1*BN+tid] + G.bred[2*BN+tid] + G.bred[3*BN+tid];
    __syncthreads();

    // epilogue: C/D layout col = fr, row = fg*4 + j (verified rounds 3-8)
    #pragma unroll
    for (int n = 0; n < 2; ++n) {
        const int c64 = wc * 32 + n * 16 + fr;
        const int c = col0 + c64;
        const float wsq = G.wsq_s[c64];
        float ps = 0.f, pq = 0.f;
        #pragma unroll
        for (int j = 0; j < 4; ++j) {
            const int rl = wr * 16 + fg * 4 + j;
            float zv = acc[n][j] - 0.5f * (G.xsq_s[rl] + wsq);
            ps += zv; pq += zv * zv;
            if (c < N) Z[(size_t)(row0 + rl) * N + c] = zv;
        }
        ps += __shfl_xor(ps, 16, 64); ps += __shfl_xor(ps, 32, 64);
        pq += __shfl_xor(pq, 16, 64); pq += __shfl_xor(pq, 32, 64);
        if (fg == 0) { G.cs[wr][c64] = ps; G.cq[wr][c64] = pq; }
    }
    __syncthreads();
    if (tid < BN) {
        int c = col0 + tid;
        if (c < N)
            stats_out[(size_t)c * NRB + rb] = make_float2(G.cs[0][tid] + G.cs[1][tid],
                                                          G.cq[0][tid] + G.cq[1][tid]);
    }
}

// ============ L1 kernel: blocks 0-223 GEMM (B direct from fp32 W1), blocks 224-255 prep W2/3/4 ============
__global__ __launch_bounds__(256) void l1_kernel(
    const float* __restrict__ X, const float* __restrict__ W1,
    const float* __restrict__ W2, const float* __restrict__ W3, const float* __restrict__ W4,
    ushort* __restrict__ Wt2, ushort* __restrict__ Wt3, ushort* __restrict__ Wt4,
    float* __restrict__ z1, float2* __restrict__ st1)
{
    __shared__ Sh sh;
    const int tid = threadIdx.x;
    const int bid = blockIdx.x;

    if (bid < 224) {
        gemm_body<0, 0>(X, W1, nullptr, nullptr, nullptr, nullptr,
                        z1, st1, 784, 392, bid / 32, bid % 32, sh, tid);
        return;
    }
    // prep: transpose W2/W3/W4 tiles to bf16 [N][K]
    for (int t = bid - 224; t < 105; t += 32) {
        const float* W; ushort* Wt; int K, N, kt, nt;
        if (t < 7)       { W = W2; Wt = Wt2; K = 392; N = 8;   kt = t;     nt = 0; }
        else if (t < 14) { W = W3; Wt = Wt3; K = 8;   N = 392; kt = 0;     nt = t - 7; }
        else             { int r = t - 14; W = W4; Wt = Wt4; K = 392; N = 784; kt = r % 7; nt = r / 7; }
        const int k0 = kt * 64, n0 = nt * 64;
        #pragma unroll
        for (int it = 0; it < 16; ++it) {
            int e = it * 256 + tid;
            int kk = e >> 6, nn = e & 63;
            int gk = k0 + kk, gn = n0 + nn;
            sh.u.ptile[kk][nn] = (gk < K && gn < N) ? W[(size_t)gk * N + gn] : 0.f;
        }
        __syncthreads();
        #pragma unroll
        for (int it = 0; it < 16; ++it) {
            int e = it * 256 + tid;
            int nn = e >> 6, kk = e & 63;
            int gk = k0 + kk, gn = n0 + nn;
            if (gk < K && gn < N) Wt[(size_t)gn * K + gk] = f2bf(sh.u.ptile[kk][nn]);
        }
        __syncthreads();
    }
}

// ============ L2/L3/L4 kernel: BN+ReLU consumer GEMM from bf16 Wt ============
__global__ __launch_bounds__(256) void gemm_norm_kernel(
    const float* __restrict__ A, const ushort* __restrict__ Wt,
    const float2* __restrict__ stats_in, const float* __restrict__ gamma, const float* __restrict__ beta,
    float* __restrict__ Z, float2* __restrict__ stats_out, int K, int N)
{
    __shared__ Sh sh;
    gemm_body<1, 1>(A, nullptr, Wt, stats_in, gamma, beta, Z, stats_out,
                    K, N, blockIdx.x / 32, blockIdx.x % 32, sh, threadIdx.x);
}

// ============ final BN + sigmoid, in place on d_out ============
__global__ __launch_bounds__(256) void bn_sigmoid_inplace(
    float* __restrict__ Zout, const float2* __restrict__ stats,
    const float* __restrict__ gamma, const float* __restrict__ beta, int N)
{
    __shared__ Sh sh;
    finalize_stats(stats, gamma, beta, N, sh, threadIdx.x);
    const int nf4 = BATCH * N / 4;
    f32x4* p = (f32x4*)Zout;
    for (int i = blockIdx.x * 256 + threadIdx.x; i < nf4; i += gridDim.x * 256) {
        f32x4 v = p[i];
        int k = (i * 4) % N;
        #pragma unroll
        for (int j = 0; j < 4; ++j) {
            float y = v[j] * sh.scaleK[k + j] + sh.shiftK[k + j];
            v[j] = 1.f / (1.f + expf(-y));
        }
        p[i] = v;
    }
}

extern "C" void kernel_launch(void* const* d_in, const int* in_sizes, int n_in,
                              void* d_out, int out_size, void* d_ws, size_t ws_size,
                              hipStream_t stream) {
    const float* X  = (const float*)d_in[0];
    const float* W1 = (const float*)d_in[1];
    const float* g1 = (const float*)d_in[2];
    const float* b1 = (const float*)d_in[3];
    const float* W2 = (const float*)d_in[4];
    const float* g2 = (const float*)d_in[5];
    const float* b2 = (const float*)d_in[6];
    const float* W3 = (const float*)d_in[7];
    const float* g3 = (const float*)d_in[8];
    const float* b3 = (const float*)d_in[9];
    const float* W4 = (const float*)d_in[10];
    const float* g4 = (const float*)d_in[11];
    const float* b4 = (const float*)d_in[12];

    float* ws = (float*)d_ws;
    float*  z1  = ws;                               // 1024*392
    float*  z2  = z1 + 1024 * 392;                  // 1024*8
    float*  z3  = z2 + 1024 * 8;                    // 1024*392
    float2* st1 = (float2*)(z3 + 1024 * 392);       // [392][32]
    float2* st2 = st1 + 392 * NRB;                  // [8][32]
    float2* st3 = st2 + 8 * NRB;                    // [392][32]
    float2* st4 = st3 + 392 * NRB;                  // [784][32]
    ushort* Wt2 = (ushort*)(st4 + 784 * NRB);       // [8][392]
    ushort* Wt3 = Wt2 + 8 * 392;                    // [392][8]
    ushort* Wt4 = Wt3 + 392 * 8;                    // [784][392]
    float* outp = (float*)d_out;

    // L1 (+ weight prep on idle blocks): X @ W1 -> z1, st1
    l1_kernel<<<256, 256, 0, stream>>>(X, W1, W2, W3, W4, Wt2, Wt3, Wt4, z1, st1);
    // L2: relu(bn(z1)) @ W2 -> z2, st2
    gemm_norm_kernel<<<32, 256, 0, stream>>>(z1, Wt2, st1, g1, b1, z2, st2, 392, 8);
    // L3: relu(bn(z2)) @ W3 -> z3, st3
    gemm_norm_kernel<<<224, 256, 0, stream>>>(z2, Wt3, st2, g2, b2, z3, st3, 8, 392);
    // L4: relu(bn(z3)) @ W4 -> d_out (pre-BN), st4
    gemm_norm_kernel<<<416, 256, 0, stream>>>(z3, Wt4, st3, g3, b3, outp, st4, 392, 784);
    // final: sigmoid(bn(out)) in place
    bn_sigmoid_inplace<<<256, 256, 0, stream>>>(outp, st4, g4, b4, 784);
}

// Round 10
// 67.293 us; speedup vs baseline: 2.3792x; 1.1300x over previous
//
#include <hip/hip_runtime.h>
#include <hip/hip_bf16.h>
#include <math.h>

#define BATCH 1024
#define BM 64
#define BN 64
#define BK 64
#define LDK 72   // bf16 units; 144B row stride -> 16B-aligned frags, 2-way read conflicts (free)
#define NRB 16   // row-blocks = BATCH/BM

typedef __attribute__((ext_vector_type(8))) short bf16x8;
typedef __attribute__((ext_vector_type(8))) ushort ushort8;
typedef __attribute__((ext_vector_type(4))) float f32x4;

static __device__ __forceinline__ ushort f2bf(float f) {
    union { float f; unsigned u; } v; v.f = f;
    unsigned r = (v.u + 0x7fffu + ((v.u >> 16) & 1u)) >> 16;  // RNE
    return (ushort)r;
}
static __device__ __forceinline__ float bf2f(ushort u) {
    union { unsigned u; float f; } v; v.u = ((unsigned)u) << 16;
    return v.f;
}

struct GemmSh {
    ushort As[2][BM][LDK];
    ushort Bs[2][BN][LDK];
    float bred[4 * BN];
    float xsq_s[BM], wsq_s[BN];
    float cs[2][BN], cq[2][BN];
};
struct Sh {
    union { float ptile[64][65]; GemmSh g; } u;
    float scaleK[784], shiftK[784];
};

// ---------- stats finalize: st layout [K][NRB] float2 (contiguous per column) ----------
static __device__ __forceinline__ void finalize_stats(
    const float2* __restrict__ stats_in, const float* __restrict__ gamma,
    const float* __restrict__ beta, int K, Sh& sh, int tid)
{
    for (int k = tid; k < K; k += 256) {
        const f32x4* p4 = (const f32x4*)(stats_in + (size_t)k * NRB);
        double s = 0.0, q = 0.0;
        #pragma unroll
        for (int i = 0; i < NRB / 2; ++i) {      // 8 x f32x4 = 16 float2, ascending rb order
            f32x4 v = p4[i];
            s += (double)v[0]; q += (double)v[1];
            s += (double)v[2]; q += (double)v[3];
        }
        double mean = s * (1.0 / BATCH);
        double var = q * (1.0 / BATCH) - mean * mean;
        float inv = (float)(1.0 / sqrt(var + 1e-5));
        float sc = gamma[k] * inv;
        sh.scaleK[k] = sc;
        sh.shiftK[k] = beta[k] - (float)mean * sc;
    }
    __syncthreads();
}

// ============ fused GEMM body (BM=64, 2x2 waves of 32x32) ============
// BSRC=0: B staged from fp32 W[K][N]; BSRC=1: from bf16 Wt[N][K].
// A_eff[r][k] = NORM ? relu(A[r][k]*scale_k + shift_k) : A[r][k]
// Z[r][c] = A_eff[r]·B[:,c] - 0.5*(||A_eff[r]||^2 + ||B[:,c]||^2); dot bf16 MFMA, rest fp32.
// stats_out[c][rb] = (sum_r z, sum_r z^2) over this block's 64 rows.
template <int NORM, int BSRC>
static __device__ void gemm_body(
    const float* __restrict__ A, const float* __restrict__ Bw32, const ushort* __restrict__ Wt,
    const float2* __restrict__ stats_in, const float* __restrict__ gamma, const float* __restrict__ beta,
    float* __restrict__ Z, float2* __restrict__ stats_out,
    int K, int N, int cx, int rb, Sh& sh, int tid)
{
    GemmSh& G = sh.u.g;
    const int lane = tid & 63;
    const int wv = tid >> 6;
    const int wr = wv >> 1, wc = wv & 1;      // 2x2 waves, each 32 rows x 32 cols
    const int row0 = rb * BM, col0 = cx * BN;
    const int ar = tid >> 3;                  // 0..31; rows ar, ar+32
    const int ak0 = (tid & 7) * 8;            // 8 k's per row
    const int bn = tid & 63;
    const int bk0 = (tid >> 6) * 16;
    const int fr = lane & 15;
    const int fg = lane >> 4;

    if (NORM) finalize_stats(stats_in, gamma, beta, K, sh, tid);

    f32x4 acc[2][2] = {};
    float asq[2] = {0.f, 0.f};
    float bsq = 0.f;
    float areg[2][8];
    float breg[16];
    ushort8 bh[2];
    const int ntiles = (K + BK - 1) / BK;

    auto load_tile = [&](int t) {
        const int kbase = t * BK;
        const int gc = col0 + bn;
        if (kbase + BK <= K) {
            #pragma unroll
            for (int l = 0; l < 2; ++l) {
                const float* p = A + (size_t)(row0 + ar + 32 * l) * K + kbase + ak0;
                f32x4 v0 = *(const f32x4*)p;
                f32x4 v1 = *(const f32x4*)(p + 4);
                #pragma unroll
                for (int j = 0; j < 4; ++j) { areg[l][j] = v0[j]; areg[l][4 + j] = v1[j]; }
                if (NORM) {
                    #pragma unroll
                    for (int j = 0; j < 8; ++j)
                        areg[l][j] = fmaxf(areg[l][j] * sh.scaleK[kbase + ak0 + j] + sh.shiftK[kbase + ak0 + j], 0.f);
                }
            }
            if (BSRC == 0) {
                #pragma unroll
                for (int i = 0; i < 16; ++i)
                    breg[i] = (gc < N) ? Bw32[(size_t)(kbase + bk0 + i) * N + gc] : 0.f;
            } else {
                if (gc < N) {
                    const ushort* q = Wt + (size_t)gc * K + kbase + bk0;
                    bh[0] = *(const ushort8*)q;
                    bh[1] = *(const ushort8*)(q + 8);
                } else {
                    bh[0] = (ushort8)0; bh[1] = (ushort8)0;
                }
            }
        } else {
            #pragma unroll
            for (int l = 0; l < 2; ++l)
                #pragma unroll
                for (int j = 0; j < 8; ++j) {
                    int gk = kbase + ak0 + j;
                    float x = 0.f;
                    if (gk < K) {
                        x = A[(size_t)(row0 + ar + 32 * l) * K + gk];
                        if (NORM) x = fmaxf(x * sh.scaleK[gk] + sh.shiftK[gk], 0.f);
                    }
                    areg[l][j] = x;
                }
            if (BSRC == 0) {
                #pragma unroll
                for (int i = 0; i < 16; ++i) {
                    int gk = kbase + bk0 + i;
                    breg[i] = (gk < K && gc < N) ? Bw32[(size_t)gk * N + gc] : 0.f;
                }
            } else {
                #pragma unroll
                for (int i = 0; i < 16; ++i) {
                    int gk = kbase + bk0 + i;
                    ushort u = (gk < K && gc < N) ? Wt[(size_t)gc * K + gk] : (ushort)0;
                    bh[i >> 3][i & 7] = u;
                }
            }
        }
    };

    auto store_tile = [&](int buf) {
        #pragma unroll
        for (int l = 0; l < 2; ++l) {
            ushort8 h;
            #pragma unroll
            for (int j = 0; j < 8; ++j) {
                h[j] = f2bf(areg[l][j]);
                asq[l] += areg[l][j] * areg[l][j];
            }
            *(ushort8*)&G.As[buf][ar + 32 * l][ak0] = h;
        }
        if (BSRC == 0) {
            ushort8 e0, e1;
            #pragma unroll
            for (int i = 0; i < 8; ++i) {
                e0[i] = f2bf(breg[i]);      bsq += breg[i] * breg[i];
                e1[i] = f2bf(breg[8 + i]);  bsq += breg[8 + i] * breg[8 + i];
            }
            *(ushort8*)&G.Bs[buf][bn][bk0] = e0;
            *(ushort8*)&G.Bs[buf][bn][bk0 + 8] = e1;
        } else {
            #pragma unroll
            for (int i = 0; i < 8; ++i) {
                float f0 = bf2f(bh[0][i]); bsq += f0 * f0;
                float f1 = bf2f(bh[1][i]); bsq += f1 * f1;
            }
            *(ushort8*)&G.Bs[buf][bn][bk0] = bh[0];
            *(ushort8*)&G.Bs[buf][bn][bk0 + 8] = bh[1];
        }
    };

    auto compute = [&](int buf) {
        bf16x8 af[2][2], bfr[2][2];
        #pragma unroll
        for (int m = 0; m < 2; ++m)
            #pragma unroll
            for (int kk = 0; kk < 2; ++kk)
                af[m][kk] = *(const bf16x8*)&G.As[buf][wr * 32 + m * 16 + fr][kk * 32 + fg * 8];
        #pragma unroll
        for (int n = 0; n < 2; ++n)
            #pragma unroll
            for (int kk = 0; kk < 2; ++kk)
                bfr[n][kk] = *(const bf16x8*)&G.Bs[buf][wc * 32 + n * 16 + fr][kk * 32 + fg * 8];
        #pragma unroll
        for (int m = 0; m < 2; ++m)
            #pragma unroll
            for (int n = 0; n < 2; ++n)
                #pragma unroll
                for (int kk = 0; kk < 2; ++kk)
                    acc[m][n] = __builtin_amdgcn_mfma_f32_16x16x32_bf16(af[m][kk], bfr[n][kk], acc[m][n], 0, 0, 0);
    };

    load_tile(0);
    store_tile(0);
    __syncthreads();
    for (int t = 0; t < ntiles; ++t) {
        if (t + 1 < ntiles) load_tile(t + 1);
        compute(t & 1);
        if (t + 1 < ntiles) store_tile((t + 1) & 1);
        __syncthreads();
    }

    // xsq: fold the 8 threads sharing each row
    #pragma unroll
    for (int l = 0; l < 2; ++l) {
        float s = asq[l];
        s += __shfl_xor(s, 1, 64);
        s += __shfl_xor(s, 2, 64);
        s += __shfl_xor(s, 4, 64);
        if ((tid & 7) == 0) G.xsq_s[ar + 32 * l] = s;
    }
    G.bred[(tid >> 6) * BN + bn] = bsq;
    __syncthreads();
    if (tid < BN) G.wsq_s[tid] = G.bred[0*BN+tid] + G.bred[1*BN+tid] + G.bred[2*BN+tid] + G.bred[3*BN+tid];
    __syncthreads();

    // epilogue: C/D layout col = fr, row = fg*4 + j (verified rounds 3-9)
    #pragma unroll
    for (int n = 0; n < 2; ++n) {
        const int c64 = wc * 32 + n * 16 + fr;
        const int c = col0 + c64;
        const float wsq = G.wsq_s[c64];
        float ps = 0.f, pq = 0.f;
        #pragma unroll
        for (int m = 0; m < 2; ++m) {
            #pragma unroll
            for (int j = 0; j < 4; ++j) {
                const int rl = wr * 32 + m * 16 + fg * 4 + j;
                float zv = acc[m][n][j] - 0.5f * (G.xsq_s[rl] + wsq);
                ps += zv; pq += zv * zv;
                if (c < N) Z[(size_t)(row0 + rl) * N + c] = zv;
            }
        }
        ps += __shfl_xor(ps, 16, 64); ps += __shfl_xor(ps, 32, 64);
        pq += __shfl_xor(pq, 16, 64); pq += __shfl_xor(pq, 32, 64);
        if (fg == 0) { G.cs[wr][c64] = ps; G.cq[wr][c64] = pq; }
    }
    __syncthreads();
    if (tid < BN) {
        int c = col0 + tid;
        if (c < N)
            stats_out[(size_t)c * NRB + rb] = make_float2(G.cs[0][tid] + G.cs[1][tid],
                                                          G.cq[0][tid] + G.cq[1][tid]);
    }
}

// ============ L1: blocks 0-111 GEMM (B direct from fp32 W1), blocks 112-143 prep W2/3/4 ============
__global__ __launch_bounds__(256) void l1_kernel(
    const float* __restrict__ X, const float* __restrict__ W1,
    const float* __restrict__ W2, const float* __restrict__ W3, const float* __restrict__ W4,
    ushort* __restrict__ Wt2, ushort* __restrict__ Wt3, ushort* __restrict__ Wt4,
    float* __restrict__ z1, float2* __restrict__ st1)
{
    __shared__ Sh sh;
    const int tid = threadIdx.x;
    const int bid = blockIdx.x;

    if (bid < 112) {
        gemm_body<0, 0>(X, W1, nullptr, nullptr, nullptr, nullptr,
                        z1, st1, 784, 392, bid / 16, bid % 16, sh, tid);
        return;
    }
    // prep: transpose W2/W3/W4 tiles to bf16 [N][K]
    for (int t = bid - 112; t < 105; t += 32) {
        const float* W; ushort* Wt; int K, N, kt, nt;
        if (t < 7)       { W = W2; Wt = Wt2; K = 392; N = 8;   kt = t;     nt = 0; }
        else if (t < 14) { W = W3; Wt = Wt3; K = 8;   N = 392; kt = 0;     nt = t - 7; }
        else             { int r = t - 14; W = W4; Wt = Wt4; K = 392; N = 784; kt = r % 7; nt = r / 7; }
        const int k0 = kt * 64, n0 = nt * 64;
        #pragma unroll
        for (int it = 0; it < 16; ++it) {
            int e = it * 256 + tid;
            int kk = e >> 6, nn = e & 63;
            int gk = k0 + kk, gn = n0 + nn;
            sh.u.ptile[kk][nn] = (gk < K && gn < N) ? W[(size_t)gk * N + gn] : 0.f;
        }
        __syncthreads();
        #pragma unroll
        for (int it = 0; it < 16; ++it) {
            int e = it * 256 + tid;
            int nn = e >> 6, kk = e & 63;
            int gk = k0 + kk, gn = n0 + nn;
            if (gk < K && gn < N) Wt[(size_t)gn * K + gk] = f2bf(sh.u.ptile[kk][nn]);
        }
        __syncthreads();
    }
}

// ============ L2/L3/L4: BN+ReLU consumer GEMM from bf16 Wt ============
__global__ __launch_bounds__(256) void gemm_norm_kernel(
    const float* __restrict__ A, const ushort* __restrict__ Wt,
    const float2* __restrict__ stats_in, const float* __restrict__ gamma, const float* __restrict__ beta,
    float* __restrict__ Z, float2* __restrict__ stats_out, int K, int N)
{
    __shared__ Sh sh;
    gemm_body<1, 1>(A, nullptr, Wt, stats_in, gamma, beta, Z, stats_out,
                    K, N, blockIdx.x / 16, blockIdx.x % 16, sh, threadIdx.x);
}

// ============ final BN + sigmoid, in place; block = 16-col x 128-row patch ============
__global__ __launch_bounds__(256) void bn_sigmoid_inplace(
    float* __restrict__ Zout, const float2* __restrict__ stats,
    const float* __restrict__ gamma, const float* __restrict__ beta)
{
    const int N = 784;
    const int c0 = blockIdx.x * 16;
    const int r0 = blockIdx.y * 128;
    const int tid = threadIdx.x;
    __shared__ float sc16[16], sh16[16];

    if (tid < 16) {
        int k = c0 + tid;
        const f32x4* p4 = (const f32x4*)(stats + (size_t)k * NRB);
        double s = 0.0, q = 0.0;
        #pragma unroll
        for (int i = 0; i < NRB / 2; ++i) {
            f32x4 v = p4[i];
            s += (double)v[0]; q += (double)v[1];
            s += (double)v[2]; q += (double)v[3];
        }
        double mean = s * (1.0 / BATCH);
        double var = q * (1.0 / BATCH) - mean * mean;
        float inv = (float)(1.0 / sqrt(var + 1e-5));
        float scv = gamma[k] * inv;
        sc16[tid] = scv;
        sh16[tid] = beta[k] - (float)mean * scv;
    }
    __syncthreads();

    const int row = r0 + (tid & 127);
    const int ch = tid >> 7;               // col-half: 8 cols
    float* p = Zout + (size_t)row * N + c0 + ch * 8;
    f32x4 v0 = *(f32x4*)p;
    f32x4 v1 = *(f32x4*)(p + 4);
    #pragma unroll
    for (int j = 0; j < 4; ++j) {
        float y0 = v0[j] * sc16[ch * 8 + j] + sh16[ch * 8 + j];
        v0[j] = 1.f / (1.f + expf(-y0));
        float y1 = v1[j] * sc16[ch * 8 + 4 + j] + sh16[ch * 8 + 4 + j];
        v1[j] = 1.f / (1.f + expf(-y1));
    }
    *(f32x4*)p = v0;
    *(f32x4*)(p + 4) = v1;
}

extern "C" void kernel_launch(void* const* d_in, const int* in_sizes, int n_in,
                              void* d_out, int out_size, void* d_ws, size_t ws_size,
                              hipStream_t stream) {
    const float* X  = (const float*)d_in[0];
    const float* W1 = (const float*)d_in[1];
    const float* g1 = (const float*)d_in[2];
    const float* b1 = (const float*)d_in[3];
    const float* W2 = (const float*)d_in[4];
    const float* g2 = (const float*)d_in[5];
    const float* b2 = (const float*)d_in[6];
    const float* W3 = (const float*)d_in[7];
    const float* g3 = (const float*)d_in[8];
    const float* b3 = (const float*)d_in[9];
    const float* W4 = (const float*)d_in[10];
    const float* g4 = (const float*)d_in[11];
    const float* b4 = (const float*)d_in[12];

    float* ws = (float*)d_ws;
    float*  z1  = ws;                               // 1024*392
    float*  z2  = z1 + 1024 * 392;                  // 1024*8
    float*  z3  = z2 + 1024 * 8;                    // 1024*392
    float2* st1 = (float2*)(z3 + 1024 * 392);       // [392][16]
    float2* st2 = st1 + 392 * NRB;                  // [8][16]
    float2* st3 = st2 + 8 * NRB;                    // [392][16]
    float2* st4 = st3 + 392 * NRB;                  // [784][16]
    ushort* Wt2 = (ushort*)(st4 + 784 * NRB);       // [8][392]
    ushort* Wt3 = Wt2 + 8 * 392;                    // [392][8]
    ushort* Wt4 = Wt3 + 392 * 8;                    // [784][392]
    float* outp = (float*)d_out;

    // L1 (+ weight prep on idle blocks): X @ W1 -> z1, st1
    l1_kernel<<<144, 256, 0, stream>>>(X, W1, W2, W3, W4, Wt2, Wt3, Wt4, z1, st1);
    // L2: relu(bn(z1)) @ W2 -> z2, st2
    gemm_norm_kernel<<<16, 256, 0, stream>>>(z1, Wt2, st1, g1, b1, z2, st2, 392, 8);
    // L3: relu(bn(z2)) @ W3 -> z3, st3
    gemm_norm_kernel<<<112, 256, 0, stream>>>(z2, Wt3, st2, g2, b2, z3, st3, 8, 392);
    // L4: relu(bn(z3)) @ W4 -> d_out (pre-BN), st4
    gemm_norm_kernel<<<208, 256, 0, stream>>>(z3, Wt4, st3, g3, b3, outp, st4, 392, 784);
    // final: sigmoid(bn(out)) in place
    bn_sigmoid_inplace<<<dim3(49, 8), 256, 0, stream>>>(outp, st4, g4, b4);
}